// Round 7
// baseline (2700.461 us; speedup 1.0000x reference)
//
#include <hip/hip_runtime.h>
#include <math.h>
#include <stdint.h>

#define BATCH 8
#define NTOK  4096
#define DIM   256
#define SK    256
#define BQ    128     // q rows per block (4 waves x 32 q, one query per lane-col)
#define BM    128     // m rows per m-tile iteration
#define BK    128     // k chunk per slice (barrier interval)
#define MH    2048    // m rows per block (half of NTOK)
#define TOPK  10      // per-slice top-k kept
#define CANDH 44      // ints per query per m-half: 1 cnt + <=20 idx + pad

typedef __attribute__((ext_vector_type(8))) _Float16 half8;  // 8 fp16 (4 VGPRs)
typedef __attribute__((ext_vector_type(4))) float float4v;
typedef __attribute__((ext_vector_type(16))) float f32x16;   // 32x32 MFMA acc

#define GLOAD_LDS16(gp, lp)                                                    \
  __builtin_amdgcn_global_load_lds(                                            \
      (const __attribute__((address_space(1))) unsigned int*)(gp),             \
      (__attribute__((address_space(3))) unsigned int*)(lp), 16, 0, 0)

__device__ __forceinline__ uint32_t umin32(uint32_t a, uint32_t b) { return a < b ? a : b; }
__device__ __forceinline__ uint32_t umax32(uint32_t a, uint32_t b) { return a > b ? a : b; }

// ---------------- threefry2x32 (JAX partitionable counter mode) ----------------
__device__ __forceinline__ uint32_t rotl32(uint32_t v, uint32_t r) {
  return (v << r) | (v >> (32u - r));
}
__device__ __forceinline__ void tf_round4(uint32_t& x0, uint32_t& x1,
                                          uint32_t r0, uint32_t r1,
                                          uint32_t r2, uint32_t r3) {
  x0 += x1; x1 = rotl32(x1, r0); x1 ^= x0;
  x0 += x1; x1 = rotl32(x1, r1); x1 ^= x0;
  x0 += x1; x1 = rotl32(x1, r2); x1 ^= x0;
  x0 += x1; x1 = rotl32(x1, r3); x1 ^= x0;
}
__device__ __forceinline__ uint32_t threefry_bits32(uint32_t c_hi, uint32_t c_lo) {
  const uint32_t k0 = 0u, k1 = 42u;
  const uint32_t k2 = k0 ^ k1 ^ 0x1BD11BDAu;
  uint32_t x0 = c_hi + k0;
  uint32_t x1 = c_lo + k1;
  tf_round4(x0, x1, 13u, 15u, 26u, 6u);  x0 += k1; x1 += k2 + 1u;
  tf_round4(x0, x1, 17u, 29u, 16u, 24u); x0 += k2; x1 += k0 + 2u;
  tf_round4(x0, x1, 13u, 15u, 26u, 6u);  x0 += k0; x1 += k1 + 3u;
  tf_round4(x0, x1, 17u, 29u, 16u, 24u); x0 += k1; x1 += k2 + 4u;
  tf_round4(x0, x1, 13u, 15u, 26u, 6u);  x0 += k2; x1 += k0 + 5u;
  return x0 ^ x1;
}

// ---------------- kernel 1: fp16 cast + row squared norms ----------------
__global__ __launch_bounds__(256) void tofp16_rowsq_kernel(
    const float* __restrict__ x, unsigned short* __restrict__ xh,
    float* __restrict__ sqf) {
  const int row  = blockIdx.x * 4 + (threadIdx.x >> 6);   // [0, BATCH*NTOK)
  const int lane = threadIdx.x & 63;
  const float* xr = x + (size_t)row * DIM;
  double acc = 0.0;
#pragma unroll
  for (int i = 0; i < 4; ++i) {
    const float v = xr[lane + i * 64];
    const _Float16 h = (_Float16)v;                       // RNE cast
    xh[(size_t)row * DIM + lane + i * 64] = *(const unsigned short*)&h;
    acc += (double)v * (double)v;
  }
#pragma unroll
  for (int off = 32; off > 0; off >>= 1) acc += __shfl_down(acc, off, 64);
  if (lane == 0) sqf[row] = (float)acc;
}

// ---------------- kernel 2: 32x32x16 swapped-operand MFMA, packed-u32 top-10 ---
// mfma(mf, qf): D col = lane&31 = query, D row = (reg&3)+8*(reg>>2)+4*(lane>>5) = m.
// Operand frag: lane l holds row/col (l&31), k = (l>>5)*8 + e.
// B staged FRAGMENT-MAJOR (32 groups x 1KB per BK=128 slice): inner reads are
// base + lane*16 (m134-optimal, conflict-free). The ~5.1e7 bank-conflict counter
// is intrinsic wide-access phase counting (bit-identical across r4/r5/r6) - ignore.
// Grid 512 = batch x qtile(32) x m-half(2). 4 waves = 4 q-groups of 32; each wave
// computes ALL 4 m32-blocks (acc[4] in AGPRs) -> 32 MFMA per barrier interval,
// 2x staged-byte reuse vs r6. Per query 2 partial top-10 lists (hi2) over 1024 m.
// Top-10 kept PACKED u32: (f32bits(d2a) & 0xFFFFF000) | m.
__global__ __launch_bounds__(256, 2) void gemm_knn_kernel(
    const unsigned short* __restrict__ xh, const float* __restrict__ sqf,
    int* __restrict__ cand) {
  __shared__ union {
    unsigned short Bf[2][16384];                     // 2 x 32 KB fragment-major slices
    uint32_t M[256][11];                             // 11 KB packed merge scratch
  } U;

  // XCD remap: XCD c serves only batch c -> one 2 MB fp16 panel per L2.
  const int wid = (blockIdx.x & 7) * 64 + (blockIdx.x >> 3);   // bijection [0,512)
  const int b   = wid >> 6;                          // batch
  const int qt  = (wid >> 1) & 31;
  const int mh  = wid & 1;                           // m half
  const int q0  = qt * BQ;
  const int mbase = mh * MH;
  const int t  = threadIdx.x;
  const int w  = t >> 6;                             // wave = q-group
  const int l  = t & 63;
  const int l5 = l & 31;
  const int hi2 = l >> 5;                            // 0..1

  const unsigned short* xhb = xh + (size_t)b * NTOK * DIM;
  const float* sqb = sqf + b * NTOK;

  // ---- fragment-major staging of one [128 m][128 k] slice (32 KB) ----
  // group g = kap*4 + ii  (kap: k16-chunk 0..7, ii: m32-block 0..3).
  // wave w stages g = c*4 + w  (c 0..7): m = m0s + w*32 + l5, k = kb + c*16 + hi2*8.
  auto stageB = [&](int buf, int m0s, int kb) {
    const int m = m0s + w * 32 + l5;
    const unsigned short* src = xhb + (size_t)m * DIM + kb + hi2 * 8;
#pragma unroll
    for (int c = 0; c < 8; ++c) {
      GLOAD_LDS16(src + c * 16,
                  (char*)&U.Bf[0][0] + buf * 32768 + (c * 4 + w) * 1024 + l * 16);
    }
  };
  stageB(0, mbase, 0);

  // ---- this wave's 32 query fragments direct from global (L2-hot, one-time) ----
  const int qg = q0 + w * 32 + l5;                   // this lane's query
  const unsigned short* qrow = xhb + (size_t)qg * DIM;
  half8 af[16];
#pragma unroll
  for (int kk = 0; kk < 16; ++kk)
    af[kk] = *(const half8*)(qrow + kk * 16 + hi2 * 8);
  const float sqq = sqb[qg];

  __syncthreads();                                   // slice 0 landed

  uint32_t tv[TOPK];
#pragma unroll
  for (int j = 0; j < TOPK; ++j) tv[j] = 0xFFFFFFFFu;

  for (int mt = 0; mt < MH / BM; ++mt) {             // 16 m-tiles
    const int m0 = mbase + mt * BM;
    f32x16 acc[4];
#pragma unroll
    for (int ii = 0; ii < 4; ++ii) acc[ii] = (f32x16)(0.0f);

#pragma unroll
    for (int ks2 = 0; ks2 < 2; ++ks2) {              // 2 BK=128 slices per tile
      const int s = mt * 2 + ks2;
      const int buf = s & 1;
      if (s + 1 < (MH / BM) * 2) {                   // prefetch next slice first
        const int sn = s + 1;
        stageB(buf ^ 1, mbase + (sn >> 1) * BM, (sn & 1) * BK);
      }
#pragma unroll
      for (int kap = 0; kap < 8; ++kap) {
        const int kk = ks2 * 8 + kap;
#pragma unroll
        for (int ii = 0; ii < 4; ++ii) {
          const half8 mf = *(const half8*)((const char*)&U.Bf[0][0] +
                                           buf * 32768 + (kap * 4 + ii) * 1024 + l * 16);
          acc[ii] = __builtin_amdgcn_mfma_f32_32x32x16_f16(mf, af[kk], acc[ii], 0, 0, 0);
        }
      }
      __syncthreads();                               // drains prefetch, guards dbuf
    }

    // epilogue (registers only): lane's m = m0 + ii*32 + hi2*4 + c*8 + r
#pragma unroll
    for (int ii = 0; ii < 4; ++ii) {
      const int mb = m0 + ii * 32 + hi2 * 4;
#pragma unroll
      for (int c = 0; c < 4; ++c) {
        const float4v sqm = *(const float4v*)(sqb + mb + c * 8);
#pragma unroll
        for (int r = 0; r < 4; ++r) {
          const int mg = mb + c * 8 + r;
          const float d2a = fmaxf(sqq + sqm[r] - 2.0f * acc[ii][c * 4 + r], 0.0f);
          uint32_t u = (__float_as_uint(d2a) & 0xFFFFF000u) | (uint32_t)mg;
          u = (mg == qg) ? 0xFFFFFFFFu : u;          // exclude self
          if (u < tv[TOPK - 1]) {                    // 20-op min/max bubble
            uint32_t v = u;
#pragma unroll
            for (int k2 = 0; k2 < TOPK; ++k2) {
              const uint32_t lo = umin32(tv[k2], v);
              v = umax32(tv[k2], v);
              tv[k2] = lo;
            }
          }
        }
      }
    }
  }

  // merge: 2 packed top-10s per query (slice = hi2, each over 1024 m)
  __syncthreads();                                   // all B reads done; reuse as M
  {
    const int slotM = (w * 32 + l5) * 2 + hi2;       // bijection [0,256)
#pragma unroll
    for (int j = 0; j < TOPK; ++j) U.M[slotM][j] = tv[j];
  }
  __syncthreads();
  if (t < BQ) {
    const int q = t;
    uint32_t t5[5] = {0xFFFFFFFFu, 0xFFFFFFFFu, 0xFFFFFFFFu, 0xFFFFFFFFu, 0xFFFFFFFFu};
    for (int s = 0; s < 2; ++s)
      for (int j = 0; j < 5; ++j) {                  // top-5 of slice suffices
        const uint32_t v = U.M[q * 2 + s][j];
        if (v < t5[4]) {
          uint32_t vv = v;
#pragma unroll
          for (int k2 = 0; k2 < 5; ++k2) {
            const uint32_t lo = umin32(t5[k2], vv);
            vv = umax32(t5[k2], vv);
            t5[k2] = lo;
          }
        }
      }
    // fp16+pack margin: e_max ~0.3+0.25 << 2.0; exact f64 recheck downstream.
    const float T = __uint_as_float(t5[4] & 0xFFFFF000u) + 2.0f;
    int cnt = 0, ov = 0;
    int* cq = cand + (size_t)(b * NTOK + q0 + q) * (2 * CANDH) + mh * CANDH;
    for (int s = 0; s < 2; ++s) {
      const uint32_t last = U.M[q * 2 + s][TOPK - 1];
      if (__uint_as_float(last & 0xFFFFF000u) < T) ov = 1;   // slice truncated?
      for (int j = 0; j < TOPK; ++j) {
        const uint32_t v = U.M[q * 2 + s][j];
        if (__uint_as_float(v & 0xFFFFF000u) <= T && cnt < 2 * TOPK)
          cq[1 + cnt++] = (int)(v & 0xFFFu);
      }
    }
    cq[0] = ov ? -1 : cnt;
  }
}

// ---------------- kernel 3: exact f64 kNN on candidates + fused gumbel score ---
__global__ __launch_bounds__(256) void exact_knn_score_kernel(
    const float* __restrict__ x, const int* __restrict__ cand,
    double* __restrict__ scores) {
  const int qg = blockIdx.x * 4 + (threadIdx.x >> 6);   // [0, BATCH*NTOK)
  const int l  = threadIdx.x & 63;
  const int b  = qg >> 12;
  const int q  = qg & (NTOK - 1);
  const float* xb = x + (size_t)b * NTOK * DIM;
  const int* cq = cand + (size_t)qg * (2 * CANDH);
  const int cnt0 = cq[0];
  const int cnt1 = cq[CANDH];
  const bool full = (cnt0 < 0) || (cnt1 < 0);

  double xq[4];
#pragma unroll
  for (int i = 0; i < 4; ++i) xq[i] = (double)xb[(size_t)q * DIM + l + i * 64];

  double t5[5] = {1e300, 1e300, 1e300, 1e300, 1e300};
  const int n_iter = full ? NTOK : (cnt0 + cnt1);
  for (int c = 0; c < n_iter; ++c) {
    int m;
    if (full) { m = c; if (m == q) continue; }
    else m = (c < cnt0) ? cq[1 + c] : cq[CANDH + 1 + (c - cnt0)];
    double acc = 0.0;
#pragma unroll
    for (int i = 0; i < 4; ++i) {
      const double d = xq[i] - (double)xb[(size_t)m * DIM + l + i * 64];
      acc += d * d;
    }
#pragma unroll
    for (int off = 32; off > 0; off >>= 1) acc += __shfl_xor(acc, off, 64);
    if (acc < t5[4]) {
      t5[4] = acc;
#pragma unroll
      for (int k2 = 4; k2 > 0; --k2)
        if (t5[k2] < t5[k2 - 1]) { double tmp = t5[k2]; t5[k2] = t5[k2 - 1]; t5[k2 - 1] = tmp; }
    }
  }
  if (l == 0) {
    // fused score: same threefry counter (qg) as the standalone kernel used.
    const uint32_t bits = threefry_bits32(0u, (uint32_t)qg);
    const uint32_t fb = (bits >> 9) | 0x3F800000u;
    float uf = __uint_as_float(fb) - 1.0f;
    const float tiny = 1.17549435082228750797e-38f;
    uf += tiny;
    if (uf < tiny) uf = tiny;
    const double g = -log(-log((double)uf));
    const double wv = sqrt(t5[4] + 1e-12);
    scores[qg] = log(wv + 1e-12) + g;
  }
}

// ---------------- kernel 5: per-batch bitonic full sort -> top-256 idx ----------
__global__ __launch_bounds__(1024) void sort_topk_kernel(
    const double* __restrict__ scores, int* __restrict__ sel) {
  __shared__ unsigned long long ko[NTOK];              // 32 KB
  __shared__ int ki[NTOK];                             // 16 KB
  const int b = blockIdx.x;
  const int t = threadIdx.x;
  for (int i = t; i < NTOK; i += 1024) {
    const double s = scores[(size_t)b * NTOK + i];
    unsigned long long u = (unsigned long long)__double_as_longlong(s);
    u = (u & 0x8000000000000000ull) ? ~u : (u | 0x8000000000000000ull);
    ko[i] = u; ki[i] = i;
  }
  __syncthreads();
  for (int k = 2; k <= NTOK; k <<= 1) {
    for (int j = k >> 1; j > 0; j >>= 1) {
      for (int base = 0; base < NTOK; base += 1024) {
        const int i = base + t;
        const int p = i ^ j;
        if (p > i) {
          const bool up = (i & k) == 0;                // up-blocks sort descending
          unsigned long long a = ko[i], c = ko[p];
          int ia = ki[i], ic = ki[p];
          const bool p_beats = (c > a) || (c == a && ic < ia);
          const bool i_beats = (a > c) || (a == c && ia < ic);
          const bool sw = up ? p_beats : i_beats;
          if (sw) { ko[i] = c; ko[p] = a; ki[i] = ic; ki[p] = ia; }
        }
      }
      __syncthreads();
    }
  }
  if (t < SK) sel[b * SK + t] = ki[t];
}

// ---------------- kernel 6: gather sampled rows ----------------
__global__ __launch_bounds__(256) void gather_kernel(const float* __restrict__ x,
                                                     const int* __restrict__ sel,
                                                     float* __restrict__ out) {
  const int blk = blockIdx.x;                          // 8*256 blocks
  const int b = blk >> 8;
  const int r = blk & 255;
  const int t = threadIdx.x;
  const int src = sel[b * SK + r];
  out[((size_t)(b * SK + r)) * DIM + t] = x[((size_t)(b * NTOK + src)) * DIM + t];
  if (blk == 0 && t == 0) out[(size_t)BATCH * SK * DIM] = 0.0f;  // 2nd output: 0.0
}

extern "C" void kernel_launch(void* const* d_in, const int* in_sizes, int n_in,
                              void* d_out, int out_size, void* d_ws, size_t ws_size,
                              hipStream_t stream) {
  const float* x = (const float*)d_in[0];
  float* out = (float*)d_out;
  char* ws = (char*)d_ws;

  double* scores  = (double*)(ws + 0);                 // 256 KB
  float*  sqf     = (float*)(ws + 262144);             // 128 KB
  int*    sel     = (int*)(ws + 393216);               // 8 KB
  unsigned short* xh = (unsigned short*)(ws + 1048576);    // 16 MB (fp16)
  int*    cand    = (int*)(ws + 17825792);             // 11.5 MB (total ~29.4 MB)

  tofp16_rowsq_kernel<<<BATCH * NTOK / 4, 256, 0, stream>>>(x, xh, sqf);
  gemm_knn_kernel<<<BATCH * (NTOK / BQ) * 2, 256, 0, stream>>>(xh, sqf, cand);
  exact_knn_score_kernel<<<BATCH * NTOK / 4, 256, 0, stream>>>(x, cand, scores);
  sort_topk_kernel<<<BATCH, 1024, 0, stream>>>(scores, sel);
  gather_kernel<<<BATCH * SK, 256, 0, stream>>>(x, sel, out);
}

// Round 8
// 454.303 us; speedup vs baseline: 5.9442x; 5.9442x over previous
//
#include <hip/hip_runtime.h>
#include <math.h>
#include <stdint.h>

#define BATCH 8
#define NTOK  4096
#define DIM   256
#define SK    256
#define BQ    128     // q rows per block (4 waves x 32 q, one query per lane-col)
#define BM    128     // m rows per m-tile iteration
#define BK    128     // k chunk per slice (barrier interval)
#define MH    2048    // m rows per block (half of NTOK)
#define TOPK  10      // per-slice top-k kept
#define CANDH 44      // ints per query per m-half: 1 cnt + <=40 idx + 3 pad

typedef __attribute__((ext_vector_type(8))) _Float16 half8;  // 8 fp16 (4 VGPRs)
typedef __attribute__((ext_vector_type(4))) float float4v;
typedef __attribute__((ext_vector_type(16))) float f32x16;   // 32x32 MFMA acc

#define GLOAD_LDS16(gp, lp)                                                    \
  __builtin_amdgcn_global_load_lds(                                            \
      (const __attribute__((address_space(1))) unsigned int*)(gp),             \
      (__attribute__((address_space(3))) unsigned int*)(lp), 16, 0, 0)

__device__ __forceinline__ uint32_t umin32(uint32_t a, uint32_t b) { return a < b ? a : b; }
__device__ __forceinline__ uint32_t umax32(uint32_t a, uint32_t b) { return a > b ? a : b; }

// ---------------- threefry2x32 (JAX partitionable counter mode) ----------------
__device__ __forceinline__ uint32_t rotl32(uint32_t v, uint32_t r) {
  return (v << r) | (v >> (32u - r));
}
__device__ __forceinline__ void tf_round4(uint32_t& x0, uint32_t& x1,
                                          uint32_t r0, uint32_t r1,
                                          uint32_t r2, uint32_t r3) {
  x0 += x1; x1 = rotl32(x1, r0); x1 ^= x0;
  x0 += x1; x1 = rotl32(x1, r1); x1 ^= x0;
  x0 += x1; x1 = rotl32(x1, r2); x1 ^= x0;
  x0 += x1; x1 = rotl32(x1, r3); x1 ^= x0;
}
__device__ __forceinline__ uint32_t threefry_bits32(uint32_t c_hi, uint32_t c_lo) {
  const uint32_t k0 = 0u, k1 = 42u;
  const uint32_t k2 = k0 ^ k1 ^ 0x1BD11BDAu;
  uint32_t x0 = c_hi + k0;
  uint32_t x1 = c_lo + k1;
  tf_round4(x0, x1, 13u, 15u, 26u, 6u);  x0 += k1; x1 += k2 + 1u;
  tf_round4(x0, x1, 17u, 29u, 16u, 24u); x0 += k2; x1 += k0 + 2u;
  tf_round4(x0, x1, 13u, 15u, 26u, 6u);  x0 += k0; x1 += k1 + 3u;
  tf_round4(x0, x1, 17u, 29u, 16u, 24u); x0 += k1; x1 += k2 + 4u;
  tf_round4(x0, x1, 13u, 15u, 26u, 6u);  x0 += k2; x1 += k0 + 5u;
  return x0 ^ x1;
}

// ---------------- kernel 1: fp16 cast + row squared norms ----------------
__global__ __launch_bounds__(256) void tofp16_rowsq_kernel(
    const float* __restrict__ x, unsigned short* __restrict__ xh,
    float* __restrict__ sqf) {
  const int row  = blockIdx.x * 4 + (threadIdx.x >> 6);   // [0, BATCH*NTOK)
  const int lane = threadIdx.x & 63;
  const float* xr = x + (size_t)row * DIM;
  double acc = 0.0;
#pragma unroll
  for (int i = 0; i < 4; ++i) {
    const float v = xr[lane + i * 64];
    const _Float16 h = (_Float16)v;                       // RNE cast
    xh[(size_t)row * DIM + lane + i * 64] = *(const unsigned short*)&h;
    acc += (double)v * (double)v;
  }
#pragma unroll
  for (int off = 32; off > 0; off >>= 1) acc += __shfl_down(acc, off, 64);
  if (lane == 0) sqf[row] = (float)acc;
}

// ---------------- kernel 2: 32x32x16 swapped-operand MFMA, packed-u32 top-10 ---
// mfma(mf, qf): D col = lane&31 = query, D row = (reg&3)+8*(reg>>2)+4*(lane>>5) = m.
// Operand frag: lane l holds row/col (l&31), k = (l>>5)*8 + e.
// B staged FRAGMENT-MAJOR (32 groups x 1KB per BK=128 slice): inner reads are
// base + lane*16 (m134-optimal, conflict-free). The ~5.1e7 bank-conflict counter
// is intrinsic wide-access phase counting (bit-identical r4/r5/r6) - ignore.
// Grid 512 = batch x qtile(32) x m-half(2). 4 waves = 4 q-groups of 32; each wave
// computes ALL 4 m32-blocks (acc[4] in AGPRs) -> 32 MFMA per barrier interval.
// STATISTICS CONTRACT (r3/r7 lesson): per query 4 lists (hi2 x c-half) of
// top-10 over 512 m each per block -> globally 8x512, replicating r6's
// proven-cheap overflow rate. Lists are PACKED u32: (f32bits & 0xFFFFF000) | m.
__global__ __launch_bounds__(256, 2) void gemm_knn_kernel(
    const unsigned short* __restrict__ xh, const float* __restrict__ sqf,
    int* __restrict__ cand) {
  __shared__ union {
    unsigned short Bf[2][16384];                     // 2 x 32 KB fragment-major slices
    uint32_t M[512][10];                             // 20 KB packed merge scratch
  } U;

  // XCD remap: XCD c serves only batch c -> one 2 MB fp16 panel per L2.
  const int wid = (blockIdx.x & 7) * 64 + (blockIdx.x >> 3);   // bijection [0,512)
  const int b   = wid >> 6;                          // batch
  const int qt  = (wid >> 1) & 31;
  const int mh  = wid & 1;                           // m half
  const int q0  = qt * BQ;
  const int mbase = mh * MH;
  const int t  = threadIdx.x;
  const int w  = t >> 6;                             // wave = q-group
  const int l  = t & 63;
  const int l5 = l & 31;
  const int hi2 = l >> 5;                            // 0..1

  const unsigned short* xhb = xh + (size_t)b * NTOK * DIM;
  const float* sqb = sqf + b * NTOK;

  // ---- fragment-major staging of one [128 m][128 k] slice (32 KB) ----
  auto stageB = [&](int buf, int m0s, int kb) {
    const int m = m0s + w * 32 + l5;
    const unsigned short* src = xhb + (size_t)m * DIM + kb + hi2 * 8;
#pragma unroll
    for (int c = 0; c < 8; ++c) {
      GLOAD_LDS16(src + c * 16,
                  (char*)&U.Bf[0][0] + buf * 32768 + (c * 4 + w) * 1024 + l * 16);
    }
  };
  stageB(0, mbase, 0);

  // ---- this wave's 32 query fragments direct from global (L2-hot, one-time) ----
  const int qg = q0 + w * 32 + l5;                   // this lane's query
  const unsigned short* qrow = xhb + (size_t)qg * DIM;
  half8 af[16];
#pragma unroll
  for (int kk = 0; kk < 16; ++kk)
    af[kk] = *(const half8*)(qrow + kk * 16 + hi2 * 8);
  const float sqq = sqb[qg];

  __syncthreads();                                   // slice 0 landed

  uint32_t tv0[TOPK], tv1[TOPK];                     // c<2 list, c>=2 list
#pragma unroll
  for (int j = 0; j < TOPK; ++j) { tv0[j] = 0xFFFFFFFFu; tv1[j] = 0xFFFFFFFFu; }

  for (int mt = 0; mt < MH / BM; ++mt) {             // 16 m-tiles
    const int m0 = mbase + mt * BM;
    f32x16 acc[4];
#pragma unroll
    for (int ii = 0; ii < 4; ++ii) acc[ii] = (f32x16)(0.0f);

#pragma unroll
    for (int ks2 = 0; ks2 < 2; ++ks2) {              // 2 BK=128 slices per tile
      const int s = mt * 2 + ks2;
      const int buf = s & 1;
      if (s + 1 < (MH / BM) * 2) {                   // prefetch next slice first
        const int sn = s + 1;
        stageB(buf ^ 1, mbase + (sn >> 1) * BM, (sn & 1) * BK);
      }
#pragma unroll
      for (int kap = 0; kap < 8; ++kap) {
        const int kk = ks2 * 8 + kap;
#pragma unroll
        for (int ii = 0; ii < 4; ++ii) {
          const half8 mf = *(const half8*)((const char*)&U.Bf[0][0] +
                                           buf * 32768 + (kap * 4 + ii) * 1024 + l * 16);
          acc[ii] = __builtin_amdgcn_mfma_f32_32x32x16_f16(mf, af[kk], acc[ii], 0, 0, 0);
        }
      }
      __syncthreads();                               // drains prefetch, guards dbuf
    }

    // epilogue (registers only): lane's m = m0 + ii*32 + hi2*4 + c*8 + r
#pragma unroll
    for (int ii = 0; ii < 4; ++ii) {
      const int mb = m0 + ii * 32 + hi2 * 4;
#pragma unroll
      for (int c = 0; c < 4; ++c) {
        const float4v sqm = *(const float4v*)(sqb + mb + c * 8);
        uint32_t* tv = (c < 2) ? tv0 : tv1;          // compile-time select (c static)
#pragma unroll
        for (int r = 0; r < 4; ++r) {
          const int mg = mb + c * 8 + r;
          const float d2a = fmaxf(sqq + sqm[r] - 2.0f * acc[ii][c * 4 + r], 0.0f);
          uint32_t u = (__float_as_uint(d2a) & 0xFFFFF000u) | (uint32_t)mg;
          u = (mg == qg) ? 0xFFFFFFFFu : u;          // exclude self
          if (u < tv[TOPK - 1]) {                    // 20-op min/max bubble
            uint32_t v = u;
#pragma unroll
            for (int k2 = 0; k2 < TOPK; ++k2) {
              const uint32_t lo = umin32(tv[k2], v);
              v = umax32(tv[k2], v);
              tv[k2] = lo;
            }
          }
        }
      }
    }
  }

  // merge: 4 packed top-10s per query (list = hi2*2 + c-half, each over 512 m)
  __syncthreads();                                   // all B reads done; reuse as M
  {
    const int base = ((w * 32 + l5) << 2) + (hi2 << 1);   // [0,512) in steps of 2
#pragma unroll
    for (int j = 0; j < TOPK; ++j) { U.M[base][j] = tv0[j]; U.M[base + 1][j] = tv1[j]; }
  }
  __syncthreads();
  if (t < BQ) {
    const int q = t;
    uint32_t t5[5] = {0xFFFFFFFFu, 0xFFFFFFFFu, 0xFFFFFFFFu, 0xFFFFFFFFu, 0xFFFFFFFFu};
    for (int s = 0; s < 4; ++s)
      for (int j = 0; j < 5; ++j) {                  // top-5 of each list suffices
        const uint32_t v = U.M[q * 4 + s][j];
        if (v < t5[4]) {
          uint32_t vv = v;
#pragma unroll
          for (int k2 = 0; k2 < 5; ++k2) {
            const uint32_t lo = umin32(t5[k2], vv);
            vv = umax32(t5[k2], vv);
            t5[k2] = lo;
          }
        }
      }
    // fp16+pack margin: e_max ~0.3+0.25 << 2.0; exact f64 recheck downstream.
    const float T = __uint_as_float(t5[4] & 0xFFFFF000u) + 2.0f;
    int cnt = 0, ov = 0;
    int* cq = cand + (size_t)(b * NTOK + q0 + q) * (2 * CANDH) + mh * CANDH;
    for (int s = 0; s < 4; ++s) {
      const uint32_t last = U.M[q * 4 + s][TOPK - 1];
      if (__uint_as_float(last & 0xFFFFF000u) < T) ov = 1;   // list truncated?
      for (int j = 0; j < TOPK; ++j) {
        const uint32_t v = U.M[q * 4 + s][j];
        if (__uint_as_float(v & 0xFFFFF000u) <= T && cnt < 4 * TOPK)
          cq[1 + cnt++] = (int)(v & 0xFFFu);
      }
    }
    cq[0] = ov ? -1 : cnt;
  }
}

// ---------------- kernel 3: exact f64 kNN on candidates + fused gumbel score ---
// Per-half fallback: an overflowed m-half rescans only its 2048 rows.
__global__ __launch_bounds__(256) void exact_knn_score_kernel(
    const float* __restrict__ x, const int* __restrict__ cand,
    double* __restrict__ scores) {
  const int qg = blockIdx.x * 4 + (threadIdx.x >> 6);   // [0, BATCH*NTOK)
  const int l  = threadIdx.x & 63;
  const int b  = qg >> 12;
  const int q  = qg & (NTOK - 1);
  const float* xb = x + (size_t)b * NTOK * DIM;
  const int* cq = cand + (size_t)qg * (2 * CANDH);

  double xq[4];
#pragma unroll
  for (int i = 0; i < 4; ++i) xq[i] = (double)xb[(size_t)q * DIM + l + i * 64];

  double t5[5] = {1e300, 1e300, 1e300, 1e300, 1e300};
  auto process = [&](int m) {
    double acc = 0.0;
#pragma unroll
    for (int i = 0; i < 4; ++i) {
      const double d = xq[i] - (double)xb[(size_t)m * DIM + l + i * 64];
      acc += d * d;
    }
#pragma unroll
    for (int off = 32; off > 0; off >>= 1) acc += __shfl_xor(acc, off, 64);
    if (acc < t5[4]) {
      t5[4] = acc;
#pragma unroll
      for (int k2 = 4; k2 > 0; --k2)
        if (t5[k2] < t5[k2 - 1]) { double tmp = t5[k2]; t5[k2] = t5[k2 - 1]; t5[k2 - 1] = tmp; }
    }
  };

  for (int h = 0; h < 2; ++h) {
    const int cnt = cq[h * CANDH];
    if (cnt >= 0) {
      for (int c = 0; c < cnt; ++c) process(cq[h * CANDH + 1 + c]);
    } else {
      const int mb = h * MH;
      for (int m = mb; m < mb + MH; ++m) {
        if (m == q) continue;
        process(m);
      }
    }
  }

  if (l == 0) {
    // fused score: same threefry counter (qg) as the standalone kernel used.
    const uint32_t bits = threefry_bits32(0u, (uint32_t)qg);
    const uint32_t fb = (bits >> 9) | 0x3F800000u;
    float uf = __uint_as_float(fb) - 1.0f;
    const float tiny = 1.17549435082228750797e-38f;
    uf += tiny;
    if (uf < tiny) uf = tiny;
    const double g = -log(-log((double)uf));
    const double wv = sqrt(t5[4] + 1e-12);
    scores[qg] = log(wv + 1e-12) + g;
  }
}

// ---------------- kernel 5: per-batch bitonic full sort -> top-256 idx ----------
__global__ __launch_bounds__(1024) void sort_topk_kernel(
    const double* __restrict__ scores, int* __restrict__ sel) {
  __shared__ unsigned long long ko[NTOK];              // 32 KB
  __shared__ int ki[NTOK];                             // 16 KB
  const int b = blockIdx.x;
  const int t = threadIdx.x;
  for (int i = t; i < NTOK; i += 1024) {
    const double s = scores[(size_t)b * NTOK + i];
    unsigned long long u = (unsigned long long)__double_as_longlong(s);
    u = (u & 0x8000000000000000ull) ? ~u : (u | 0x8000000000000000ull);
    ko[i] = u; ki[i] = i;
  }
  __syncthreads();
  for (int k = 2; k <= NTOK; k <<= 1) {
    for (int j = k >> 1; j > 0; j >>= 1) {
      for (int base = 0; base < NTOK; base += 1024) {
        const int i = base + t;
        const int p = i ^ j;
        if (p > i) {
          const bool up = (i & k) == 0;                // up-blocks sort descending
          unsigned long long a = ko[i], c = ko[p];
          int ia = ki[i], ic = ki[p];
          const bool p_beats = (c > a) || (c == a && ic < ia);
          const bool i_beats = (a > c) || (a == c && ia < ic);
          const bool sw = up ? p_beats : i_beats;
          if (sw) { ko[i] = c; ko[p] = a; ki[i] = ic; ki[p] = ia; }
        }
      }
      __syncthreads();
    }
  }
  if (t < SK) sel[b * SK + t] = ki[t];
}

// ---------------- kernel 6: gather sampled rows ----------------
__global__ __launch_bounds__(256) void gather_kernel(const float* __restrict__ x,
                                                     const int* __restrict__ sel,
                                                     float* __restrict__ out) {
  const int blk = blockIdx.x;                          // 8*256 blocks
  const int b = blk >> 8;
  const int r = blk & 255;
  const int t = threadIdx.x;
  const int src = sel[b * SK + r];
  out[((size_t)(b * SK + r)) * DIM + t] = x[((size_t)(b * NTOK + src)) * DIM + t];
  if (blk == 0 && t == 0) out[(size_t)BATCH * SK * DIM] = 0.0f;  // 2nd output: 0.0
}

extern "C" void kernel_launch(void* const* d_in, const int* in_sizes, int n_in,
                              void* d_out, int out_size, void* d_ws, size_t ws_size,
                              hipStream_t stream) {
  const float* x = (const float*)d_in[0];
  float* out = (float*)d_out;
  char* ws = (char*)d_ws;

  double* scores  = (double*)(ws + 0);                 // 256 KB
  float*  sqf     = (float*)(ws + 262144);             // 128 KB
  int*    sel     = (int*)(ws + 393216);               // 8 KB
  unsigned short* xh = (unsigned short*)(ws + 1048576);    // 16 MB (fp16)
  int*    cand    = (int*)(ws + 17825792);             // 11.5 MB (total ~29.4 MB)

  tofp16_rowsq_kernel<<<BATCH * NTOK / 4, 256, 0, stream>>>(x, xh, sqf);
  gemm_knn_kernel<<<BATCH * (NTOK / BQ) * 2, 256, 0, stream>>>(xh, sqf, cand);
  exact_knn_score_kernel<<<BATCH * NTOK / 4, 256, 0, stream>>>(x, cand, scores);
  sort_topk_kernel<<<BATCH, 1024, 0, stream>>>(scores, sel);
  gather_kernel<<<BATCH * SK, 256, 0, stream>>>(x, sel, out);
}

// Round 9
// 448.305 us; speedup vs baseline: 6.0237x; 1.0134x over previous
//
#include <hip/hip_runtime.h>
#include <math.h>
#include <stdint.h>

#define BATCH 8
#define NTOK  4096
#define DIM   256
#define SK    256
#define BQ    128     // q rows per block (4 waves x 32 q, one query per lane-col)
#define BM    128     // m rows per m-tile iteration
#define BK    64      // k chunk per slice (barrier interval); 2x16KB LDS dbuf
#define MH    2048    // m rows per block (half of NTOK)
#define TOPK  10      // per-slice top-k kept
#define CANDH 44      // ints per query per m-half: 1 cnt + <=40 idx + 3 pad

typedef __attribute__((ext_vector_type(8))) _Float16 half8;  // 8 fp16 (4 VGPRs)
typedef __attribute__((ext_vector_type(4))) float float4v;
typedef __attribute__((ext_vector_type(16))) float f32x16;   // 32x32 MFMA acc

#define GLOAD_LDS16(gp, lp)                                                    \
  __builtin_amdgcn_global_load_lds(                                            \
      (const __attribute__((address_space(1))) unsigned int*)(gp),             \
      (__attribute__((address_space(3))) unsigned int*)(lp), 16, 0, 0)

__device__ __forceinline__ uint32_t umin32(uint32_t a, uint32_t b) { return a < b ? a : b; }
__device__ __forceinline__ uint32_t umax32(uint32_t a, uint32_t b) { return a > b ? a : b; }

// ---------------- threefry2x32 (JAX partitionable counter mode) ----------------
__device__ __forceinline__ uint32_t rotl32(uint32_t v, uint32_t r) {
  return (v << r) | (v >> (32u - r));
}
__device__ __forceinline__ void tf_round4(uint32_t& x0, uint32_t& x1,
                                          uint32_t r0, uint32_t r1,
                                          uint32_t r2, uint32_t r3) {
  x0 += x1; x1 = rotl32(x1, r0); x1 ^= x0;
  x0 += x1; x1 = rotl32(x1, r1); x1 ^= x0;
  x0 += x1; x1 = rotl32(x1, r2); x1 ^= x0;
  x0 += x1; x1 = rotl32(x1, r3); x1 ^= x0;
}
__device__ __forceinline__ uint32_t threefry_bits32(uint32_t c_hi, uint32_t c_lo) {
  const uint32_t k0 = 0u, k1 = 42u;
  const uint32_t k2 = k0 ^ k1 ^ 0x1BD11BDAu;
  uint32_t x0 = c_hi + k0;
  uint32_t x1 = c_lo + k1;
  tf_round4(x0, x1, 13u, 15u, 26u, 6u);  x0 += k1; x1 += k2 + 1u;
  tf_round4(x0, x1, 17u, 29u, 16u, 24u); x0 += k2; x1 += k0 + 2u;
  tf_round4(x0, x1, 13u, 15u, 26u, 6u);  x0 += k0; x1 += k1 + 3u;
  tf_round4(x0, x1, 17u, 29u, 16u, 24u); x0 += k1; x1 += k2 + 4u;
  tf_round4(x0, x1, 13u, 15u, 26u, 6u);  x0 += k2; x1 += k0 + 5u;
  return x0 ^ x1;
}

// ---------------- kernel 1: fp16 cast + row squared norms ----------------
__global__ __launch_bounds__(256) void tofp16_rowsq_kernel(
    const float* __restrict__ x, unsigned short* __restrict__ xh,
    float* __restrict__ sqf) {
  const int row  = blockIdx.x * 4 + (threadIdx.x >> 6);   // [0, BATCH*NTOK)
  const int lane = threadIdx.x & 63;
  const float* xr = x + (size_t)row * DIM;
  double acc = 0.0;
#pragma unroll
  for (int i = 0; i < 4; ++i) {
    const float v = xr[lane + i * 64];
    const _Float16 h = (_Float16)v;                       // RNE cast
    xh[(size_t)row * DIM + lane + i * 64] = *(const unsigned short*)&h;
    acc += (double)v * (double)v;
  }
#pragma unroll
  for (int off = 32; off > 0; off >>= 1) acc += __shfl_down(acc, off, 64);
  if (lane == 0) sqf[row] = (float)acc;
}

// ---------------- kernel 2: 32x32x16 swapped-operand MFMA, packed-u32 top-10 ---
// mfma(mf, qf): D col = lane&31 = query, D row = (reg&3)+8*(reg>>2)+4*(lane>>5) = m.
// B staged FRAGMENT-MAJOR (16 groups x 1KB per BK=64 slice): inner reads are
// base + lane*16 (m134-optimal, conflict-free).
// Grid 512 = batch x qtile(32) x m-half(2). 4 waves; each wave computes all 4
// m32-blocks (acc[4]). BK=64 -> 32KB LDS/block: occupancy probe (r8 was 2
// blocks/CU at 64KB; if LDS-bound this doubles residency).
// STATISTICS CONTRACT (r3/r7 lesson): per query 4 lists (hi2 x c-half) of
// top-10 over 512 m each per block -> globally 8x512 (r6/r8 proven-cheap).
// EPILOGUE DIET (r8 post-mortem: 46% VALU = eval stream): no fmax (min real
// d2 ~247 >> fp err), no per-eval self-cndmask (self handled at merge via
// top-6 + kidx; exact pass skips m==q), pack = single v_and_or_b32.
__global__ __launch_bounds__(256, 2) void gemm_knn_kernel(
    const unsigned short* __restrict__ xh, const float* __restrict__ sqf,
    int* __restrict__ cand) {
  __shared__ union {
    unsigned short Bf[2][8192];                      // 2 x 16 KB fragment-major slices
    uint32_t M[512][10];                             // 20 KB packed merge scratch
  } U;

  // XCD remap: XCD c serves only batch c -> one 2 MB fp16 panel per L2.
  const int wid = (blockIdx.x & 7) * 64 + (blockIdx.x >> 3);   // bijection [0,512)
  const int b   = wid >> 6;                          // batch
  const int qt  = (wid >> 1) & 31;
  const int mh  = wid & 1;                           // m half
  const int q0  = qt * BQ;
  const int mbase = mh * MH;
  const int t  = threadIdx.x;
  const int w  = t >> 6;                             // wave = staging m-block
  const int l  = t & 63;
  const int l5 = l & 31;
  const int hi2 = l >> 5;                            // 0..1

  const unsigned short* xhb = xh + (size_t)b * NTOK * DIM;
  const float* sqb = sqf + b * NTOK;

  // ---- fragment-major staging of one [128 m][64 k] slice (16 KB) ----
  // group g = kap*4 + ii (kap: k16-chunk 0..3, ii: m32-block 0..3).
  // wave w stages ii=w, kap=c: m = m0s + w*32 + l5, k = kb + c*16 + hi2*8.
  auto stageB = [&](int buf, int m0s, int kb) {
    const int m = m0s + w * 32 + l5;
    const unsigned short* src = xhb + (size_t)m * DIM + kb + hi2 * 8;
#pragma unroll
    for (int c = 0; c < 4; ++c) {
      GLOAD_LDS16(src + c * 16,
                  (char*)&U.Bf[0][0] + buf * 16384 + (c * 4 + w) * 1024 + l * 16);
    }
  };
  stageB(0, mbase, 0);

  // ---- this wave's 32 query fragments direct from global (L2-hot, one-time) ----
  const int qg = q0 + w * 32 + l5;                   // this lane's query
  const unsigned short* qrow = xhb + (size_t)qg * DIM;
  half8 af[16];
#pragma unroll
  for (int kk = 0; kk < 16; ++kk)
    af[kk] = *(const half8*)(qrow + kk * 16 + hi2 * 8);
  const float sqq = sqb[qg];

  __syncthreads();                                   // slice 0 landed

  uint32_t tv0[TOPK], tv1[TOPK];                     // c<2 list, c>=2 list
#pragma unroll
  for (int j = 0; j < TOPK; ++j) { tv0[j] = 0xFFFFFFFFu; tv1[j] = 0xFFFFFFFFu; }

  for (int mt = 0; mt < MH / BM; ++mt) {             // 16 m-tiles
    const int m0 = mbase + mt * BM;
    f32x16 acc[4];
#pragma unroll
    for (int ii = 0; ii < 4; ++ii) acc[ii] = (f32x16)(0.0f);

#pragma unroll
    for (int ks = 0; ks < 4; ++ks) {                 // 4 BK=64 slices per tile
      const int s = mt * 4 + ks;
      const int buf = s & 1;
      if (s + 1 < (MH / BM) * 4) {                   // prefetch next slice first
        const int sn = s + 1;
        stageB(buf ^ 1, mbase + (sn >> 2) * BM, (sn & 3) * BK);
      }
#pragma unroll
      for (int kap = 0; kap < 4; ++kap) {
        const int kk = ks * 4 + kap;
#pragma unroll
        for (int ii = 0; ii < 4; ++ii) {
          const half8 mf = *(const half8*)((const char*)&U.Bf[0][0] +
                                           buf * 16384 + (kap * 4 + ii) * 1024 + l * 16);
          acc[ii] = __builtin_amdgcn_mfma_f32_32x32x16_f16(mf, af[kk], acc[ii], 0, 0, 0);
        }
      }
      __syncthreads();                               // drains prefetch, guards dbuf
    }

    // epilogue (registers only): lane's m = m0 + ii*32 + hi2*4 + c*8 + r
#pragma unroll
    for (int ii = 0; ii < 4; ++ii) {
      const int mb = m0 + ii * 32 + hi2 * 4;
#pragma unroll
      for (int c = 0; c < 4; ++c) {
        const float4v sqm = *(const float4v*)(sqb + mb + c * 8);
        uint32_t* tv = (c < 2) ? tv0 : tv1;          // compile-time select (c static)
#pragma unroll
        for (int r = 0; r < 4; ++r) {
          const int mg = mb + c * 8 + r;
          const float d2a = sqq + sqm[r] - 2.0f * acc[ii][c * 4 + r];  // fma+add
          const uint32_t u = (__float_as_uint(d2a) & 0xFFFFF000u) | (uint32_t)mg;
          if (u < tv[TOPK - 1]) {                    // 20-op min/max bubble
            uint32_t v = u;
#pragma unroll
            for (int k2 = 0; k2 < TOPK; ++k2) {
              const uint32_t lo = umin32(tv[k2], v);
              v = umax32(tv[k2], v);
              tv[k2] = lo;
            }
          }
        }
      }
    }
  }

  // merge: 4 packed top-10s per query (list = hi2*2 + c-half, each over 512 m)
  __syncthreads();                                   // all B reads done; reuse as M
  {
    const int base = ((w * 32 + l5) << 2) + (hi2 << 1);   // [0,512) in steps of 2
#pragma unroll
    for (int j = 0; j < TOPK; ++j) { U.M[base][j] = tv0[j]; U.M[base + 1][j] = tv1[j]; }
  }
  __syncthreads();
  if (t < BQ) {
    const int q = t;
    const int qglob = q0 + q;                        // this query's global index
    // self (d2a ~ 0, or excluded if fp error made it negative) lives in this
    // block iff qglob is in [mbase, mbase+MH). Keep top-6; threshold from the
    // 6th when self may occupy a slot, else the 5th. Conservative either way.
    const int kidx = ((qglob >> 11) == mh) ? 5 : 4;
    uint32_t t6[6];
#pragma unroll
    for (int j = 0; j < 6; ++j) t6[j] = 0xFFFFFFFFu;
    for (int s = 0; s < 4; ++s)
      for (int j = 0; j < 6; ++j) {                  // top-6 of each list suffices
        const uint32_t v = U.M[q * 4 + s][j];
        if (v < t6[5]) {
          uint32_t vv = v;
#pragma unroll
          for (int k2 = 0; k2 < 6; ++k2) {
            const uint32_t lo = umin32(t6[k2], vv);
            vv = umax32(t6[k2], vv);
            t6[k2] = lo;
          }
        }
      }
    // fp16+pack margin (e_max ~0.3 + trunc 0.25 << 2.0); exact f64 recheck follows.
    const float T = __uint_as_float(t6[kidx] & 0xFFFFF000u) + 2.0f;
    int cnt = 0, ov = 0;
    int* cq = cand + (size_t)(b * NTOK + qglob) * (2 * CANDH) + mh * CANDH;
    for (int s = 0; s < 4; ++s) {
      const uint32_t last = U.M[q * 4 + s][TOPK - 1];
      if (__uint_as_float(last & 0xFFFFF000u) < T) ov = 1;   // list truncated?
      for (int j = 0; j < TOPK; ++j) {
        const uint32_t v = U.M[q * 4 + s][j];
        if (__uint_as_float(v & 0xFFFFF000u) <= T && cnt < 4 * TOPK)
          cq[1 + cnt++] = (int)(v & 0xFFFu);         // may include self; filtered later
      }
    }
    cq[0] = ov ? -1 : cnt;
  }
}

// ---------------- kernel 3: exact f64 kNN on candidates + fused gumbel score ---
// Per-half fallback: an overflowed m-half rescans only its 2048 rows.
__global__ __launch_bounds__(256) void exact_knn_score_kernel(
    const float* __restrict__ x, const int* __restrict__ cand,
    double* __restrict__ scores) {
  const int qg = blockIdx.x * 4 + (threadIdx.x >> 6);   // [0, BATCH*NTOK)
  const int l  = threadIdx.x & 63;
  const int b  = qg >> 12;
  const int q  = qg & (NTOK - 1);
  const float* xb = x + (size_t)b * NTOK * DIM;
  const int* cq = cand + (size_t)qg * (2 * CANDH);

  double xq[4];
#pragma unroll
  for (int i = 0; i < 4; ++i) xq[i] = (double)xb[(size_t)q * DIM + l + i * 64];

  double t5[5] = {1e300, 1e300, 1e300, 1e300, 1e300};
  auto process = [&](int m) {
    double acc = 0.0;
#pragma unroll
    for (int i = 0; i < 4; ++i) {
      const double d = xq[i] - (double)xb[(size_t)m * DIM + l + i * 64];
      acc += d * d;
    }
#pragma unroll
    for (int off = 32; off > 0; off >>= 1) acc += __shfl_xor(acc, off, 64);
    if (acc < t5[4]) {
      t5[4] = acc;
#pragma unroll
      for (int k2 = 4; k2 > 0; --k2)
        if (t5[k2] < t5[k2 - 1]) { double tmp = t5[k2]; t5[k2] = t5[k2 - 1]; t5[k2 - 1] = tmp; }
    }
  };

  for (int h = 0; h < 2; ++h) {
    const int cnt = cq[h * CANDH];
    if (cnt >= 0) {
      for (int c = 0; c < cnt; ++c) {
        const int m = cq[h * CANDH + 1 + c];
        if (m == q) continue;                        // self may be in cand list now
        process(m);
      }
    } else {
      const int mb = h * MH;
      for (int m = mb; m < mb + MH; ++m) {
        if (m == q) continue;
        process(m);
      }
    }
  }

  if (l == 0) {
    // fused score: same threefry counter (qg) as the standalone kernel used.
    const uint32_t bits = threefry_bits32(0u, (uint32_t)qg);
    const uint32_t fb = (bits >> 9) | 0x3F800000u;
    float uf = __uint_as_float(fb) - 1.0f;
    const float tiny = 1.17549435082228750797e-38f;
    uf += tiny;
    if (uf < tiny) uf = tiny;
    const double g = -log(-log((double)uf));
    const double wv = sqrt(t5[4] + 1e-12);
    scores[qg] = log(wv + 1e-12) + g;
  }
}

// ---------------- kernel 5: per-batch bitonic full sort -> top-256 idx ----------
__global__ __launch_bounds__(1024) void sort_topk_kernel(
    const double* __restrict__ scores, int* __restrict__ sel) {
  __shared__ unsigned long long ko[NTOK];              // 32 KB
  __shared__ int ki[NTOK];                             // 16 KB
  const int b = blockIdx.x;
  const int t = threadIdx.x;
  for (int i = t; i < NTOK; i += 1024) {
    const double s = scores[(size_t)b * NTOK + i];
    unsigned long long u = (unsigned long long)__double_as_longlong(s);
    u = (u & 0x8000000000000000ull) ? ~u : (u | 0x8000000000000000ull);
    ko[i] = u; ki[i] = i;
  }
  __syncthreads();
  for (int k = 2; k <= NTOK; k <<= 1) {
    for (int j = k >> 1; j > 0; j >>= 1) {
      for (int base = 0; base < NTOK; base += 1024) {
        const int i = base + t;
        const int p = i ^ j;
        if (p > i) {
          const bool up = (i & k) == 0;                // up-blocks sort descending
          unsigned long long a = ko[i], c = ko[p];
          int ia = ki[i], ic = ki[p];
          const bool p_beats = (c > a) || (c == a && ic < ia);
          const bool i_beats = (a > c) || (a == c && ia < ic);
          const bool sw = up ? p_beats : i_beats;
          if (sw) { ko[i] = c; ko[p] = a; ki[i] = ic; ki[p] = ia; }
        }
      }
      __syncthreads();
    }
  }
  if (t < SK) sel[b * SK + t] = ki[t];
}

// ---------------- kernel 6: gather sampled rows ----------------
__global__ __launch_bounds__(256) void gather_kernel(const float* __restrict__ x,
                                                     const int* __restrict__ sel,
                                                     float* __restrict__ out) {
  const int blk = blockIdx.x;                          // 8*256 blocks
  const int b = blk >> 8;
  const int r = blk & 255;
  const int t = threadIdx.x;
  const int src = sel[b * SK + r];
  out[((size_t)(b * SK + r)) * DIM + t] = x[((size_t)(b * NTOK + src)) * DIM + t];
  if (blk == 0 && t == 0) out[(size_t)BATCH * SK * DIM] = 0.0f;  // 2nd output: 0.0
}

extern "C" void kernel_launch(void* const* d_in, const int* in_sizes, int n_in,
                              void* d_out, int out_size, void* d_ws, size_t ws_size,
                              hipStream_t stream) {
  const float* x = (const float*)d_in[0];
  float* out = (float*)d_out;
  char* ws = (char*)d_ws;

  double* scores  = (double*)(ws + 0);                 // 256 KB
  float*  sqf     = (float*)(ws + 262144);             // 128 KB
  int*    sel     = (int*)(ws + 393216);               // 8 KB
  unsigned short* xh = (unsigned short*)(ws + 1048576);    // 16 MB (fp16)
  int*    cand    = (int*)(ws + 17825792);             // 11.5 MB (total ~29.4 MB)

  tofp16_rowsq_kernel<<<BATCH * NTOK / 4, 256, 0, stream>>>(x, xh, sqf);
  gemm_knn_kernel<<<BATCH * (NTOK / BQ) * 2, 256, 0, stream>>>(xh, sqf, cand);
  exact_knn_score_kernel<<<BATCH * NTOK / 4, 256, 0, stream>>>(x, cand, scores);
  sort_topk_kernel<<<BATCH, 1024, 0, stream>>>(scores, sel);
  gather_kernel<<<BATCH * SK, 256, 0, stream>>>(x, sel, out);
}